// Round 1
// baseline (100.755 us; speedup 1.0000x reference)
//
#include <hip/hip_runtime.h>
#include <hip/hip_bf16.h>

typedef __attribute__((ext_vector_type(8))) short short8;
typedef __attribute__((ext_vector_type(4))) float floatx4;

#define B_ROWS 8192
#define DIM    128
#define NSPLIT 4
#define BM     64
#define BN     64
#define JTILES_PER_SPLIT (B_ROWS / NSPLIT / BN)   // 32

// ---------------- prep: f32 -> bf16 convert + squared norms ----------------
__global__ __launch_bounds__(256) void prep_kernel(const float* __restrict__ x,
                                                   __hip_bfloat16* __restrict__ xb,
                                                   float* __restrict__ sq) {
    const int row  = blockIdx.x * 4 + (threadIdx.x >> 6);
    const int lane = threadIdx.x & 63;
    const float2 v = *reinterpret_cast<const float2*>(x + row * DIM + lane * 2);
    __hip_bfloat162 b2;
    b2.x = __float2bfloat16(v.x);
    b2.y = __float2bfloat16(v.y);
    *reinterpret_cast<__hip_bfloat162*>(xb + row * DIM + lane * 2) = b2;
    float s = v.x * v.x + v.y * v.y;
    #pragma unroll
    for (int m = 1; m < 64; m <<= 1) s += __shfl_xor(s, m, 64);
    if (lane == 0) sq[row] = s;
}

// ---------------- main: fused Gram + hardest pos/neg tracking ----------------
// grid = (B_ROWS/BM, NSPLIT), block = 256 (4 waves).
// Each block owns 64 rows; each wave 16 rows. Loop over this split's j-tiles.
// Track t = sq_j - 2*dot; d2 = sq_i + t (sq_i added at the end).
__global__ __launch_bounds__(256) void main_kernel(
    const __hip_bfloat16* __restrict__ xb,
    const float* __restrict__ sq,
    const int*  __restrict__ lab,
    float* __restrict__ d2p,   // [NSPLIT][B_ROWS]
    float* __restrict__ d2n) { // [NSPLIT][B_ROWS]
    __shared__ __align__(16) char ldsB[BN * DIM * 2];  // 16 KB, XOR-swizzled

    const int tid   = threadIdx.x;
    const int lane  = tid & 63;
    const int wave  = tid >> 6;            // 0..3
    const int ibase = blockIdx.x * BM;
    const int split = blockIdx.y;
    const int rowbase = ibase + wave * 16;

    const int l15 = lane & 15;
    const int lhi = lane >> 4;             // 0..3

    // A fragments (16 rows x 128 k) held in registers: 4 k-chunks of 8 bf16.
    // Layout for mfma_f32_16x16x32_bf16 A: row = lane&15, k = kk*32 + (lane>>4)*8 + e
    short8 afrag[4];
    {
        const __hip_bfloat16* aptr = xb + (size_t)(rowbase + l15) * DIM + lhi * 8;
        #pragma unroll
        for (int kk = 0; kk < 4; ++kk)
            afrag[kk] = *reinterpret_cast<const short8*>(aptr + kk * 32);
    }

    // Per-lane output rows (C/D layout: row = (lane>>4)*4 + r, col = lane&15)
    int   irow[4]; float sqi[4]; int labi[4];
    #pragma unroll
    for (int r = 0; r < 4; ++r) {
        irow[r] = rowbase + lhi * 4 + r;
        sqi[r]  = sq[irow[r]];
        labi[r] = lab[irow[r]];
    }

    float tp[4], tn[4];
    #pragma unroll
    for (int r = 0; r < 4; ++r) { tp[r] = -INFINITY; tn[r] = INFINITY; }

    const int jstart = split * (B_ROWS / NSPLIT);

    for (int jt = 0; jt < JTILES_PER_SPLIT; ++jt) {
        const int jbase = jstart + jt * BN;

        __syncthreads();   // previous iteration's LDS reads done
        // stage B tile: 64 rows x 256B, 16B chunks, XOR swizzle byte^=(row&7)<<4
        #pragma unroll
        for (int q = 0; q < 4; ++q) {
            const int c   = q * 256 + tid;   // 16B-chunk index, 1024 total
            const int row = c >> 4;
            const int cik = c & 15;
            const float4 v = *reinterpret_cast<const float4*>(
                xb + (size_t)(jbase + row) * DIM + cik * 8);
            const int off = (c * 16) ^ ((row & 7) << 4);
            *reinterpret_cast<float4*>(ldsB + off) = v;
        }
        __syncthreads();

        #pragma unroll
        for (int ct = 0; ct < 4; ++ct) {
            const int jloc = ct * 16 + l15;
            const int jcol = jbase + jloc;
            floatx4 acc = {0.f, 0.f, 0.f, 0.f};
            #pragma unroll
            for (int kk = 0; kk < 4; ++kk) {
                const int off = (jloc * 256 + kk * 64 + lhi * 16) ^ ((jloc & 7) << 4);
                const short8 bfrag = *reinterpret_cast<const short8*>(ldsB + off);
                acc = __builtin_amdgcn_mfma_f32_16x16x32_bf16(afrag[kk], bfrag, acc, 0, 0, 0);
            }
            const float sqj = sq[jcol];
            const int  labj = lab[jcol];
            #pragma unroll
            for (int r = 0; r < 4; ++r) {
                const float t = fmaf(-2.0f, acc[r], sqj);
                const bool same = (labj == labi[r]);
                if (same && (jcol != irow[r])) tp[r] = fmaxf(tp[r], t);
                if (!same)                     tn[r] = fminf(tn[r], t);
            }
        }
    }

    // reduce across the 16 lanes holding the same rows (masks 1,2,4,8 stay in-group)
    #pragma unroll
    for (int m = 1; m < 16; m <<= 1) {
        #pragma unroll
        for (int r = 0; r < 4; ++r) {
            tp[r] = fmaxf(tp[r], __shfl_xor(tp[r], m, 64));
            tn[r] = fminf(tn[r], __shfl_xor(tn[r], m, 64));
        }
    }
    if (l15 == 0) {
        #pragma unroll
        for (int r = 0; r < 4; ++r) {
            d2p[split * B_ROWS + irow[r]] = sqi[r] + tp[r];  // -inf if no pos
            d2n[split * B_ROWS + irow[r]] = sqi[r] + tn[r];  // +inf if no neg
        }
    }
}

// ---------------- combine: splits -> per-row loss -> scalar ----------------
__global__ __launch_bounds__(256) void combine_kernel(
    const float* __restrict__ d2p, const float* __restrict__ d2n,
    float* __restrict__ out) {
    __shared__ float ssum[4];
    __shared__ int   scnt[4];
    float sum = 0.f; int cnt = 0;
    for (int i = threadIdx.x; i < B_ROWS; i += 256) {
        float p = -INFINITY, n = INFINITY;
        #pragma unroll
        for (int s = 0; s < NSPLIT; ++s) {
            p = fmaxf(p, d2p[s * B_ROWS + i]);
            n = fminf(n, d2n[s * B_ROWS + i]);
        }
        const bool valid = (p > -INFINITY) && (n < INFINITY);
        if (valid) {
            const float hp = sqrtf(fmaxf(p, 0.f));
            const float hn = sqrtf(fmaxf(n, 0.f));
            sum += fmaxf(hp - hn + 1.0f, 0.f);
            cnt += 1;
        }
    }
    #pragma unroll
    for (int m = 1; m < 64; m <<= 1) {
        sum += __shfl_xor(sum, m, 64);
        cnt += __shfl_xor(cnt, m, 64);
    }
    const int wave = threadIdx.x >> 6;
    if ((threadIdx.x & 63) == 0) { ssum[wave] = sum; scnt[wave] = cnt; }
    __syncthreads();
    if (threadIdx.x == 0) {
        float S = 0.f; int C = 0;
        #pragma unroll
        for (int w = 0; w < 4; ++w) { S += ssum[w]; C += scnt[w]; }
        out[0] = (C > 0) ? (S / (float)C) : 0.0f;
    }
}

// ---------------- launch ----------------
extern "C" void kernel_launch(void* const* d_in, const int* in_sizes, int n_in,
                              void* d_out, int out_size, void* d_ws, size_t ws_size,
                              hipStream_t stream) {
    const float* x   = (const float*)d_in[0];
    const int*   lab = (const int*)d_in[1];
    float*       out = (float*)d_out;

    char* ws = (char*)d_ws;
    __hip_bfloat16* xb = (__hip_bfloat16*)ws;                          // 2 MB
    float* sq  = (float*)(ws + 2 * 1024 * 1024);                       // 32 KB
    float* d2p = (float*)(ws + 2 * 1024 * 1024 + 64 * 1024);           // 128 KB
    float* d2n = (float*)(ws + 2 * 1024 * 1024 + 64 * 1024 + 128 * 1024);

    prep_kernel<<<B_ROWS / 4, 256, 0, stream>>>(x, xb, sq);
    main_kernel<<<dim3(B_ROWS / BM, NSPLIT), 256, 0, stream>>>(xb, sq, lab, d2p, d2n);
    combine_kernel<<<1, 256, 0, stream>>>(d2p, d2n, out);
}

// Round 2
// 66.456 us; speedup vs baseline: 1.5161x; 1.5161x over previous
//
#include <hip/hip_runtime.h>
#include <hip/hip_bf16.h>

typedef __attribute__((ext_vector_type(8))) short short8;
typedef __attribute__((ext_vector_type(16))) float floatx16;

#define B_ROWS 8192
#define DIM    128
#define NSPLIT 16
#define JSPAN  (B_ROWS / NSPLIT)        // 512 cols per split
#define NTILE  (JSPAN / 32)             // 16 j-tiles per split
#define WAVES  4
#define ROWS_PER_WAVE 64                // 2 x 32-row MFMA sets
#define BM     (WAVES * ROWS_PER_WAVE)  // 256 rows per block
#define NRB    (B_ROWS / BM)            // 32 row-blocks

// ws layout
#define OFF_SQ   (2u << 20)                       // 2 MB of bf16 xb first
#define OFF_D2P  (OFF_SQ + (64u << 10))
#define OFF_D2N  (OFF_D2P + (512u << 10))
#define OFF_ACC  (OFF_D2N + (512u << 10))         // float sum, int cnt, int done

// ---------------- prep: f32 -> bf16 + squared norms + zero accumulators ----------------
__global__ __launch_bounds__(256) void prep_kernel(const float* __restrict__ x,
                                                   __hip_bfloat16* __restrict__ xb,
                                                   float* __restrict__ sq,
                                                   float* __restrict__ acc_sum,
                                                   int* __restrict__ acc_cnt,
                                                   int* __restrict__ done) {
    if (blockIdx.x == 0 && threadIdx.x == 0) { acc_sum[0] = 0.f; acc_cnt[0] = 0; done[0] = 0; }
    const int row  = blockIdx.x * 4 + (threadIdx.x >> 6);
    const int lane = threadIdx.x & 63;
    const float2 v = *reinterpret_cast<const float2*>(x + row * DIM + lane * 2);
    __hip_bfloat162 b2;
    b2.x = __float2bfloat16(v.x);
    b2.y = __float2bfloat16(v.y);
    *reinterpret_cast<__hip_bfloat162*>(xb + row * DIM + lane * 2) = b2;
    float s = v.x * v.x + v.y * v.y;
    #pragma unroll
    for (int m = 1; m < 64; m <<= 1) s += __shfl_xor(s, m, 64);
    if (lane == 0) sq[row] = s;
}

// ---------------- main: barrier-free Gram + hardest pos/neg, B from L2 ----------------
// grid = (NRB, NSPLIT), block = 256 (4 independent waves).
// Wave owns 64 rows (A + tp/tn + labels in regs); streams the split's 512 cols.
// Track t = sq_j - 2*dot; add sq_i only at the final write.
__global__ __launch_bounds__(256, 2) void main_kernel(
    const __hip_bfloat16* __restrict__ xb,
    const float* __restrict__ sq,
    const int*  __restrict__ lab,
    float* __restrict__ d2p,   // [NSPLIT][B_ROWS]
    float* __restrict__ d2n) { // [NSPLIT][B_ROWS]
    const int tid  = threadIdx.x;
    const int lane = tid & 63;
    const int wave = tid >> 6;
    const int l31  = lane & 31;
    const int hi   = lane >> 5;
    const int rowbase = blockIdx.x * BM + wave * ROWS_PER_WAVE;
    const int split   = blockIdx.y;
    const int jstart  = split * JSPAN;

    // A fragments for 2 sets of 32 owned rows.
    // mfma_f32_32x32x16_bf16 A layout: row = lane&31, k = (lane>>5)*8 + e
    short8 a0[8], a1[8];
    {
        const __hip_bfloat16* ap0 = xb + (size_t)(rowbase + l31) * DIM + hi * 8;
        const __hip_bfloat16* ap1 = ap0 + 32 * DIM;
        #pragma unroll
        for (int ks = 0; ks < 8; ++ks) {
            a0[ks] = *reinterpret_cast<const short8*>(ap0 + ks * 16);
            a1[ks] = *reinterpret_cast<const short8*>(ap1 + ks * 16);
        }
    }
    // Labels of owned rows per C/D reg (row = (r&3) + 8*(r>>2) + 4*hi)
    int labi0[16], labi1[16];
    #pragma unroll
    for (int r = 0; r < 16; ++r) {
        const int rl = (r & 3) + 8 * (r >> 2) + 4 * hi;
        labi0[r] = lab[rowbase + rl];
        labi1[r] = lab[rowbase + 32 + rl];
    }

    float tp0[16], tn0[16], tp1[16], tn1[16];
    #pragma unroll
    for (int r = 0; r < 16; ++r) { tp0[r] = -INFINITY; tp1[r] = -INFINITY; tn0[r] = INFINITY; tn1[r] = INFINITY; }

    // B column pointer: col = jbase + (lane&31), k = (lane>>5)*8 + e
    const __hip_bfloat16* bcol = xb + (size_t)(jstart + l31) * DIM + hi * 8;

    for (int jt = 0; jt < NTILE; ++jt) {
        const int jbase = jstart + jt * 32;
        const float sqj = sq[jbase + l31];
        const int  labj = lab[jbase + l31];
        const __hip_bfloat16* bp = bcol + (size_t)jt * 32 * DIM;
        short8 b[8];
        #pragma unroll
        for (int ks = 0; ks < 8; ++ks) b[ks] = *reinterpret_cast<const short8*>(bp + ks * 16);

        floatx16 acc0, acc1;
        #pragma unroll
        for (int i = 0; i < 16; ++i) { acc0[i] = 0.f; acc1[i] = 0.f; }
        #pragma unroll
        for (int ks = 0; ks < 8; ++ks) {
            acc0 = __builtin_amdgcn_mfma_f32_32x32x16_bf16(a0[ks], b[ks], acc0, 0, 0, 0);
            acc1 = __builtin_amdgcn_mfma_f32_32x32x16_bf16(a1[ks], b[ks], acc1, 0, 0, 0);
        }

        // epilogue, M-set 0
        if (jbase == rowbase) {   // wave-uniform: this tile contains diagonal elems of set 0
            #pragma unroll
            for (int r = 0; r < 16; ++r) {
                const float t = fmaf(-2.f, acc0[r], sqj);
                const bool same = (labj == labi0[r]);
                const bool dg = (l31 == ((r & 3) + 8 * (r >> 2) + 4 * hi));
                if (same && !dg) tp0[r] = fmaxf(tp0[r], t);
                if (!same)       tn0[r] = fminf(tn0[r], t);
            }
        } else {
            #pragma unroll
            for (int r = 0; r < 16; ++r) {
                const float t = fmaf(-2.f, acc0[r], sqj);
                const bool same = (labj == labi0[r]);
                if (same) tp0[r] = fmaxf(tp0[r], t);
                else      tn0[r] = fminf(tn0[r], t);
            }
        }
        // epilogue, M-set 1
        if (jbase == rowbase + 32) {
            #pragma unroll
            for (int r = 0; r < 16; ++r) {
                const float t = fmaf(-2.f, acc1[r], sqj);
                const bool same = (labj == labi1[r]);
                const bool dg = (l31 == ((r & 3) + 8 * (r >> 2) + 4 * hi));
                if (same && !dg) tp1[r] = fmaxf(tp1[r], t);
                if (!same)       tn1[r] = fminf(tn1[r], t);
            }
        } else {
            #pragma unroll
            for (int r = 0; r < 16; ++r) {
                const float t = fmaf(-2.f, acc1[r], sqj);
                const bool same = (labj == labi1[r]);
                if (same) tp1[r] = fmaxf(tp1[r], t);
                else      tn1[r] = fminf(tn1[r], t);
            }
        }
    }

    // reduce across the 32 lanes sharing each row (xor masks stay within the 32-group)
    #pragma unroll
    for (int r = 0; r < 16; ++r) {
        #pragma unroll
        for (int mk = 1; mk < 32; mk <<= 1) {
            tp0[r] = fmaxf(tp0[r], __shfl_xor(tp0[r], mk, 64));
            tn0[r] = fminf(tn0[r], __shfl_xor(tn0[r], mk, 64));
            tp1[r] = fmaxf(tp1[r], __shfl_xor(tp1[r], mk, 64));
            tn1[r] = fminf(tn1[r], __shfl_xor(tn1[r], mk, 64));
        }
    }
    if (l31 == 0) {
        #pragma unroll
        for (int r = 0; r < 16; ++r) {
            const int rl = (r & 3) + 8 * (r >> 2) + 4 * hi;
            const int i0 = rowbase + rl;
            const int i1 = rowbase + 32 + rl;
            d2p[split * B_ROWS + i0] = sq[i0] + tp0[r];  // -inf if no positive seen
            d2n[split * B_ROWS + i0] = sq[i0] + tn0[r];  // +inf if no negative seen
            d2p[split * B_ROWS + i1] = sq[i1] + tp1[r];
            d2n[split * B_ROWS + i1] = sq[i1] + tn1[r];
        }
    }
}

// ---------------- combine: splits -> per-row loss -> scalar (last-block finalize) ----------------
__global__ __launch_bounds__(256) void combine_kernel(
    const float* __restrict__ d2p, const float* __restrict__ d2n,
    float* __restrict__ acc_sum, int* __restrict__ acc_cnt, int* __restrict__ done,
    float* __restrict__ out) {
    const int row = blockIdx.x * 256 + threadIdx.x;
    float p = -INFINITY, n = INFINITY;
    #pragma unroll
    for (int s = 0; s < NSPLIT; ++s) {
        p = fmaxf(p, d2p[s * B_ROWS + row]);
        n = fminf(n, d2n[s * B_ROWS + row]);
    }
    const bool valid = (p > -INFINITY) && (n < INFINITY);
    float v = 0.f; int c = 0;
    if (valid) {
        v = fmaxf(sqrtf(fmaxf(p, 0.f)) - sqrtf(fmaxf(n, 0.f)) + 1.0f, 0.f);
        c = 1;
    }
    #pragma unroll
    for (int mk = 1; mk < 64; mk <<= 1) { v += __shfl_xor(v, mk, 64); c += __shfl_xor(c, mk, 64); }
    __shared__ float sv[4];
    __shared__ int   sc[4];
    const int wv = threadIdx.x >> 6;
    if ((threadIdx.x & 63) == 0) { sv[wv] = v; sc[wv] = c; }
    __syncthreads();
    if (threadIdx.x == 0) {
        atomicAdd(acc_sum, sv[0] + sv[1] + sv[2] + sv[3]);
        atomicAdd(acc_cnt, sc[0] + sc[1] + sc[2] + sc[3]);
        __threadfence();
        const int old = atomicAdd(done, 1);
        if (old == (int)gridDim.x - 1) {
            const float fs = atomicAdd(acc_sum, 0.f);   // coherent read
            const int   fc = atomicAdd(acc_cnt, 0);
            out[0] = (fc > 0) ? fs / (float)fc : 0.f;
        }
    }
}

// ---------------- launch ----------------
extern "C" void kernel_launch(void* const* d_in, const int* in_sizes, int n_in,
                              void* d_out, int out_size, void* d_ws, size_t ws_size,
                              hipStream_t stream) {
    const float* x   = (const float*)d_in[0];
    const int*   lab = (const int*)d_in[1];
    float*       out = (float*)d_out;

    char* ws = (char*)d_ws;
    __hip_bfloat16* xb = (__hip_bfloat16*)ws;
    float* sq      = (float*)(ws + OFF_SQ);
    float* d2p     = (float*)(ws + OFF_D2P);
    float* d2n     = (float*)(ws + OFF_D2N);
    float* acc_sum = (float*)(ws + OFF_ACC);
    int*   acc_cnt = (int*)(ws + OFF_ACC + 4);
    int*   done    = (int*)(ws + OFF_ACC + 8);

    prep_kernel<<<B_ROWS / 4, 256, 0, stream>>>(x, xb, sq, acc_sum, acc_cnt, done);
    main_kernel<<<dim3(NRB, NSPLIT), 256, 0, stream>>>(xb, sq, lab, d2p, d2n);
    combine_kernel<<<B_ROWS / 256, 256, 0, stream>>>(d2p, d2n, acc_sum, acc_cnt, done, out);
}